// Round 8
// baseline (55.775 us; speedup 1.0000x reference)
//
#include <hip/hip_runtime.h>
#include <math.h>

// GaussianNLLLoss: out = -mean( c0 + log(normcdf(-lambda*resid/sigma)) - resid^2/(2*sigma2) )
// R8: inline-asm loads + counted vmcnt waits (T4 pattern at register level).
// R3-R7 lesson: hipcc NEVER holds >2 float4s in flight (VGPR=28-48 every
// round) -- it re-serializes source-level pipelines with vmcnt(0) drains.
// Now loads are asm volatile (opaque, un-collapsible), consumed after
// s_waitcnt vmcnt(8) + sched_barrier(0), so 8 KB/wave stays in flight
// under every compute phase.

typedef float f32x4 __attribute__((ext_vector_type(4)));

#define GLOAD(dst, addr) \
    asm volatile("global_load_dwordx4 %0, %1, off" : "=v"(dst) : "v"(addr) : "memory")

#define VMWAIT(n) do { \
    asm volatile("s_waitcnt vmcnt(" #n ")" ::: "memory"); \
    __builtin_amdgcn_sched_barrier(0); } while (0)

__device__ __forceinline__ float ll_elem(float r, float karg, float nk2, float inv2s2) {
    float r2 = r * r;
    float x  = karg * r;
    float ax = fabsf(x);
    float t  = __builtin_amdgcn_rcpf(fmaf(0.3275911f, ax, 1.0f));  // v_rcp_f32
    float p  = fmaf(t, 1.061405429f, -1.453152027f);
    p = fmaf(t, p, 1.421413741f);
    p = fmaf(t, p, -0.284496736f);
    p = fmaf(t, p, 0.254829592f);
    p *= t;
    float e  = __expf(nk2 * r2);                 // exp(-x^2), reusing r^2
    float ea = fmaf(-p, e, 1.0f);                // erf(|x|)  (A&S 7.1.26, |err|<1.5e-7)
    float ev = copysignf(ea, x);                 // erf(x)
    return __logf(fmaf(0.5f, ev, 0.5f)) - r2 * inv2s2;  // log(ncdf) - r^2/(2s2)
}

__global__ __launch_bounds__(256) void gnll_stage1(
    const float4* __restrict__ yp, const float4* __restrict__ yt,
    const float* __restrict__ lsv, const float* __restrict__ lsu,
    float* __restrict__ partials, int n4)
{
    const float std_v  = __expf(lsv[0]);
    const float std_u  = __expf(lsu[0]);
    const float sigma2 = std_v * std_v + std_u * std_u;
    const float sigma  = sqrtf(sigma2);
    const float llamda = std_u / std_v;
    const float karg   = -llamda / sigma * 0.70710678118654752f;  // *r -> erf arg
    const float nk2    = -karg * karg;                            // *r^2 -> -x^2
    const float c0     = -0.5f * logf(1.57079632679489662f)
                         - 0.5f * logf(sigma2);
    const float inv2s2 = 0.5f / sigma2;

    const int tid = blockIdx.x * blockDim.x + threadIdx.x;
    const int nth = gridDim.x * blockDim.x;

    float acc = 0.0f;

#define LOADG(P0,P1,P2,P3,T0,T1,T2,T3, g) { \
    const float4* bp_ = yp + (size_t)(g) * nth * 4 + tid; \
    const float4* bt_ = yt + (size_t)(g) * nth * 4 + tid; \
    GLOAD(P0, bp_);            GLOAD(T0, bt_); \
    GLOAD(P1, bp_ + nth);      GLOAD(T1, bt_ + nth); \
    GLOAD(P2, bp_ + 2 * nth);  GLOAD(T2, bt_ + 2 * nth); \
    GLOAD(P3, bp_ + 3 * nth);  GLOAD(T3, bt_ + 3 * nth); }

#define COMP1(P, T) { \
    acc += ll_elem(T.x - P.x, karg, nk2, inv2s2) + ll_elem(T.y - P.y, karg, nk2, inv2s2) \
         + ll_elem(T.z - P.z, karg, nk2, inv2s2) + ll_elem(T.w - P.w, karg, nk2, inv2s2); }

#define COMPG(P0,P1,P2,P3,T0,T1,T2,T3) { \
    COMP1(P0, T0) COMP1(P1, T1) COMP1(P2, T2) COMP1(P3, T3) }

    const int ngroups = n4 / (nth * 4);
    if (ngroups == 4 && n4 == nth * 16) {
        // Bench shape: fully-unrolled 2-deep register pipeline, 8 KB/wave in flight.
        f32x4 pa0, pa1, pa2, pa3, ta0, ta1, ta2, ta3;
        f32x4 pb0, pb1, pb2, pb3, tb0, tb1, tb2, tb3;

        LOADG(pa0,pa1,pa2,pa3, ta0,ta1,ta2,ta3, 0)   // A <- g0
        LOADG(pb0,pb1,pb2,pb3, tb0,tb1,tb2,tb3, 1)   // B <- g1 (stays in flight)
        VMWAIT(8);                                   // A done, B outstanding
        COMPG(pa0,pa1,pa2,pa3, ta0,ta1,ta2,ta3)
        LOADG(pa0,pa1,pa2,pa3, ta0,ta1,ta2,ta3, 2)   // A <- g2 under B's wait
        VMWAIT(8);                                   // B done, A outstanding
        COMPG(pb0,pb1,pb2,pb3, tb0,tb1,tb2,tb3)
        LOADG(pb0,pb1,pb2,pb3, tb0,tb1,tb2,tb3, 3)   // B <- g3
        VMWAIT(8);                                   // A done
        COMPG(pa0,pa1,pa2,pa3, ta0,ta1,ta2,ta3)
        VMWAIT(0);                                   // drain B
        COMPG(pb0,pb1,pb2,pb3, tb0,tb1,tb2,tb3)
        acc += 64.0f * c0;
    } else {
        // Generic fallback (unused at bench shape)
        int cnt = 0;
        for (int i = tid; i < n4; i += nth) {
            float4 p = yp[i];
            float4 t = yt[i];
            acc += ll_elem(t.x - p.x, karg, nk2, inv2s2)
                 + ll_elem(t.y - p.y, karg, nk2, inv2s2)
                 + ll_elem(t.z - p.z, karg, nk2, inv2s2)
                 + ll_elem(t.w - p.w, karg, nk2, inv2s2);
            cnt += 4;
        }
        acc = fmaf((float)cnt, c0, acc);
    }

    // wave64 butterfly reduce
    #pragma unroll
    for (int off = 32; off > 0; off >>= 1)
        acc += __shfl_down(acc, off, 64);

    __shared__ float ws[4];
    int lane = threadIdx.x & 63;
    int wid  = threadIdx.x >> 6;
    if (lane == 0) ws[wid] = acc;
    __syncthreads();
    if (threadIdx.x == 0)
        partials[blockIdx.x] = (ws[0] + ws[1]) + (ws[2] + ws[3]);
}

__global__ __launch_bounds__(256) void gnll_stage2(
    const float* __restrict__ partials, float* __restrict__ out,
    int nparts, float neg_inv_n)
{
    float acc = 0.0f;
    for (int i = threadIdx.x; i < nparts; i += 256)
        acc += partials[i];

    #pragma unroll
    for (int off = 32; off > 0; off >>= 1)
        acc += __shfl_down(acc, off, 64);

    __shared__ float ws[4];
    int lane = threadIdx.x & 63;
    int wid  = threadIdx.x >> 6;
    if (lane == 0) ws[wid] = acc;
    __syncthreads();
    if (threadIdx.x == 0)
        out[0] = ((ws[0] + ws[1]) + (ws[2] + ws[3])) * neg_inv_n;
}

extern "C" void kernel_launch(void* const* d_in, const int* in_sizes, int n_in,
                              void* d_out, int out_size, void* d_ws, size_t ws_size,
                              hipStream_t stream) {
    const float4* yp = (const float4*)d_in[0];
    const float4* yt = (const float4*)d_in[1];
    const float* lsv = (const float*)d_in[2];
    const float* lsu = (const float*)d_in[3];
    float* out = (float*)d_out;
    float* partials = (float*)d_ws;   // 2048 floats = 8 KB scratch

    long long n = (long long)in_sizes[0];   // 33554432, divisible by 4
    int n4 = (int)(n / 4);                  // 8388608 float4s per tensor
    float neg_inv_n = -1.0f / (float)n;

    const int block = 256;
    const int grid  = 2048;  // 524288 threads -> ngroups = 4, exact, no tail
    gnll_stage1<<<grid, block, 0, stream>>>(yp, yt, lsv, lsu, partials, n4);
    gnll_stage2<<<1, block, 0, stream>>>(partials, out, grid, neg_inv_n);
}